// Round 2
// baseline (280.404 us; speedup 1.0000x reference)
//
#include <hip/hip_runtime.h>

// 8 stacked 3x3 same-pad convs on independent 3x3 images == one affine map
// out = A*x + c (A: 9x9, c: 9). compose_affine builds it in d_ws each call;
// apply kernel streams 4M rows through it.
//
// R6: no-LDS row-resident apply. R5's in-wave pipelining was neutral ->
// latency was already TLP-hidden; the remaining gap vs copy BW (4.4 vs
// 6.3 TB/s) is attributed to the LDS transpose round-trip + barriers
// stalling all resident waves in lockstep. Eliminate the transpose:
// each lane owns 4 full rows = 36 consecutive floats = 9 contiguous
// 16B-aligned dwordx4 loads. Rows are then register-resident with static
// component indexing (no scratch, rule #20 respected). No LDS, no
// barriers, no shuffles. Plain (cached) loads so L1/MSHR merges the
// 144B-lane-stride 16B accesses into full-line fetches; plain stores so
// L2 write-combines the same pattern.

typedef float v4f __attribute__((ext_vector_type(4)));

// ---------------- Kernel 1: compose the affine map --------------------------
__global__ void compose_affine(const float* __restrict__ w,   // [8,3,3] flat
                               const float* __restrict__ b,   // [8]
                               float* __restrict__ aff)       // [90]: A(81), c(9)
{
    __shared__ float W[72];
    __shared__ float B[8];
    __shared__ float A[2][81];
    __shared__ float C[2][9];
    const int t = threadIdx.x;

    if (t < 72) W[t] = w[t];
    if (t >= 72 && t < 80) B[t - 72] = b[t - 72];
    if (t < 81) A[0][t] = (t / 9 == t % 9) ? 1.0f : 0.0f;
    if (t < 9)  C[0][t] = 0.0f;
    __syncthreads();

    int cur = 0;
    for (int d = 0; d < 8; ++d) {
        if (t < 81) {
            const int i = t / 9, j = t % 9;
            const int r = i / 3, cc = i % 3;
            float acc = 0.0f;
            float accc = (j == 0) ? B[d] : 0.0f;
            #pragma unroll
            for (int k = 0; k < 9; ++k) {
                const int rr = k / 3, kc = k % 3;
                const int dr = rr - r + 1, dc = kc - cc + 1;
                float m = 0.0f;
                if (dr >= 0 && dr < 3 && dc >= 0 && dc < 3)
                    m = W[d * 9 + dr * 3 + dc];
                acc = fmaf(m, A[cur][k * 9 + j], acc);
                if (j == 0) accc = fmaf(m, C[cur][k], accc);
            }
            A[1 - cur][t] = acc;
            if (j == 0) C[1 - cur][i] = accc;
        }
        __syncthreads();
        cur = 1 - cur;
    }
    if (t < 81) aff[t] = A[cur][t];
    if (t < 9)  aff[81 + t] = C[cur][t];
}

// ---------------- Kernel 2: no-LDS row-resident affine apply ----------------
// Thread g owns rows [4g, 4g+4) = floats [36g, 36g+36) = v4f [9g, 9g+9).
// Per-lane base 144*g bytes is 16B-aligned; all row element extraction is
// compile-time-static v4f component indexing -> pure register renames.
__global__ __launch_bounds__(256) void apply_affine_rows(
    const v4f* __restrict__ in4,
    const float* __restrict__ aff,
    v4f* __restrict__ out4,
    long long n_groups,        // full 4-row groups
    long long rem_rows)        // leftover rows (0..3), handled by thread g==n_groups
{
    const long long g = (long long)blockIdx.x * blockDim.x + threadIdx.x;

    if (g < n_groups) {
        const v4f* __restrict__ ip = in4 + g * 9;
        v4f d[9];
        #pragma unroll
        for (int j = 0; j < 9; ++j) d[j] = ip[j];   // 9 contiguous dwordx4

        #pragma unroll
        for (int r = 0; r < 4; ++r) {
            float xv[9];
            #pragma unroll
            for (int k = 0; k < 9; ++k) {
                const int fi = 9 * r + k;           // static
                xv[k] = d[fi >> 2][fi & 3];
            }
            float y[9];
            #pragma unroll
            for (int i = 0; i < 9; ++i) y[i] = aff[81 + i];
            #pragma unroll
            for (int k = 0; k < 9; ++k) {
                #pragma unroll
                for (int i = 0; i < 9; ++i)
                    y[i] = fmaf(aff[i * 9 + k], xv[k], y[i]);  // aff -> SGPR
            }
            #pragma unroll
            for (int k = 0; k < 9; ++k) {
                const int fi = 9 * r + k;           // static
                d[fi >> 2][fi & 3] = y[k];
            }
        }

        v4f* __restrict__ op = out4 + g * 9;
        #pragma unroll
        for (int j = 0; j < 9; ++j) op[j] = d[j];   // 9 contiguous dwordx4
    } else if (g == n_groups && rem_rows > 0) {
        // scalar tail: up to 3 rows
        const float* __restrict__ inf = (const float*)in4;
        float* __restrict__ outf = (float*)out4;
        for (int r = 0; r < (int)rem_rows; ++r) {
            const long long base = (n_groups * 4 + r) * 9;
            float xv[9];
            for (int k = 0; k < 9; ++k) xv[k] = inf[base + k];
            float y[9];
            for (int i = 0; i < 9; ++i) y[i] = aff[81 + i];
            for (int k = 0; k < 9; ++k)
                for (int i = 0; i < 9; ++i)
                    y[i] = fmaf(aff[i * 9 + k], xv[k], y[i]);
            for (int k = 0; k < 9; ++k) outf[base + k] = y[k];
        }
    }
}

extern "C" void kernel_launch(void* const* d_in, const int* in_sizes, int n_in,
                              void* d_out, int out_size, void* d_ws, size_t ws_size,
                              hipStream_t stream) {
    const float* x = (const float*)d_in[0];   // [N,9] fp32
    const float* w = (const float*)d_in[1];   // [8,1,1,3,3] fp32
    const float* b = (const float*)d_in[2];   // [8] fp32
    float* out = (float*)d_out;
    float* aff = (float*)d_ws;                // 90 floats

    const long long n_elems  = (long long)in_sizes[0];   // 36,000,000
    const long long n_rows   = n_elems / 9;              // 4,000,000
    const long long n_groups = n_rows / 4;               // 1,000,000
    const long long rem_rows = n_rows % 4;               // 0

    const long long n_threads = n_groups + (rem_rows ? 1 : 0);
    const unsigned blocks = (unsigned)((n_threads + 255) / 256);   // 3907

    compose_affine<<<1, 128, 0, stream>>>(w, b, aff);
    apply_affine_rows<<<dim3(blocks), dim3(256), 0, stream>>>(
        (const v4f*)x, aff, (v4f*)out, n_groups, rem_rows);
}

// Round 3
// 248.516 us; speedup vs baseline: 1.1283x; 1.1283x over previous
//
#include <hip/hip_runtime.h>

// 8 stacked 3x3 same-pad convs on independent 3x3 images == one affine map
// out = A*x + c (A: 9x9, c: 9). compose_affine builds it in d_ws each call;
// apply_affine streams 4M rows through it.
//
// R7: R4's coalesced nt staging + R6's register-resident compute.
// R6 proved direct 144B-stride global access is TA-limited (~87us) -> LDS
// coalescing stays. But the transpose can be all-b128: lane L owns 4 whole
// rows = 36 contiguous floats = LDS v4f [9L, 9L+9). Stage-in linear
// (quad-stride 1, conflict-free), compute-read t4[9L+q] (quad-stride
// 9 == 1 mod 8, conflict-free for b128), rows register-resident with
// static v4f component indexing, write-back b128, stage-out linear.
// LDS ops per tile: 90 mixed -> 36 x b128 (~634 -> ~432 LDS cycles),
// and the 72 scattered b32 address computations disappear.

typedef float v4f __attribute__((ext_vector_type(4)));

// ---------------- Kernel 1: compose the affine map --------------------------
__global__ void compose_affine(const float* __restrict__ w,   // [8,3,3] flat
                               const float* __restrict__ b,   // [8]
                               float* __restrict__ aff)       // [90]: A(81), c(9)
{
    __shared__ float W[72];
    __shared__ float B[8];
    __shared__ float A[2][81];
    __shared__ float C[2][9];
    const int t = threadIdx.x;

    if (t < 72) W[t] = w[t];
    if (t >= 72 && t < 80) B[t - 72] = b[t - 72];
    if (t < 81) A[0][t] = (t / 9 == t % 9) ? 1.0f : 0.0f;
    if (t < 9)  C[0][t] = 0.0f;
    __syncthreads();

    int cur = 0;
    for (int d = 0; d < 8; ++d) {
        if (t < 81) {
            const int i = t / 9, j = t % 9;
            const int r = i / 3, cc = i % 3;
            float acc = 0.0f;
            float accc = (j == 0) ? B[d] : 0.0f;
            #pragma unroll
            for (int k = 0; k < 9; ++k) {
                const int rr = k / 3, kc = k % 3;
                const int dr = rr - r + 1, dc = kc - cc + 1;
                float m = 0.0f;
                if (dr >= 0 && dr < 3 && dc >= 0 && dc < 3)
                    m = W[d * 9 + dr * 3 + dc];
                acc = fmaf(m, A[cur][k * 9 + j], acc);
                if (j == 0) accc = fmaf(m, C[cur][k], accc);
            }
            A[1 - cur][t] = acc;
            if (j == 0) C[1 - cur][i] = accc;
        }
        __syncthreads();
        cur = 1 - cur;
    }
    if (t < 81) aff[t] = A[cur][t];
    if (t < 9)  aff[81 + t] = C[cur][t];
}

// ---------------- Kernel 2: wave-autonomous b128-transpose affine apply -----
// Tile: 256 rows = 576 v4f = 2304 floats. Lane L stages v4f (L + 64j),
// j=0..8 (coalesced, LDS quad-stride 1); computes rows [4L, 4L+4) from
// LDS v4f [9L, 9L+9) (quad-stride 9 == 1 mod 8 -> conflict-free b128).
__global__ __launch_bounds__(64) void apply_affine(
    const v4f* __restrict__ in4,
    const float* __restrict__ aff,
    v4f* __restrict__ out4,
    long long n_f4)
{
    __shared__ float tile[2304];   // 9216 B
    v4f* __restrict__ t4 = (v4f*)tile;
    const int L = threadIdx.x;
    const long long base = (long long)blockIdx.x * 576;

    // ---- stage in: 9 coalesced nt float4 loads, all in flight together ----
    v4f r[9];
    if (base + 576 <= n_f4) {
        #pragma unroll
        for (int j = 0; j < 9; ++j)
            r[j] = __builtin_nontemporal_load(in4 + base + L + (long long)j * 64);
    } else {
        #pragma unroll
        for (int j = 0; j < 9; ++j) {
            const long long g = base + L + (long long)j * 64;
            r[j] = (g < n_f4) ? __builtin_nontemporal_load(in4 + g) : (v4f)0.0f;
        }
    }
    #pragma unroll
    for (int j = 0; j < 9; ++j) t4[L + j * 64] = r[j];
    __syncthreads();   // single-wave wg: just the lgkm/vm drain

    // ---- gather 4 whole rows into registers: 9 x ds_read_b128 ----
    v4f d[9];
    #pragma unroll
    for (int q = 0; q < 9; ++q) d[q] = t4[9 * L + q];

    // ---- compute 4 rows, fully register-resident, static indexing ----
    #pragma unroll
    for (int rr = 0; rr < 4; ++rr) {
        float xv[9];
        #pragma unroll
        for (int k = 0; k < 9; ++k) {
            const int fi = 9 * rr + k;             // static
            xv[k] = d[fi >> 2][fi & 3];
        }
        float y[9];
        #pragma unroll
        for (int i = 0; i < 9; ++i) y[i] = aff[81 + i];
        #pragma unroll
        for (int k = 0; k < 9; ++k) {
            #pragma unroll
            for (int i = 0; i < 9; ++i)
                y[i] = fmaf(aff[i * 9 + k], xv[k], y[i]);   // aff -> SGPR (uniform)
        }
        #pragma unroll
        for (int k = 0; k < 9; ++k) {
            const int fi = 9 * rr + k;             // static
            d[fi >> 2][fi & 3] = y[k];
        }
    }

    // ---- write back: 9 x ds_write_b128 ----
    #pragma unroll
    for (int q = 0; q < 9; ++q) t4[9 * L + q] = d[q];
    __syncthreads();

    // ---- stage out: 9 coalesced nt float4 stores ----
    #pragma unroll
    for (int j = 0; j < 9; ++j) r[j] = t4[L + j * 64];
    if (base + 576 <= n_f4) {
        #pragma unroll
        for (int j = 0; j < 9; ++j)
            __builtin_nontemporal_store(r[j], out4 + base + L + (long long)j * 64);
    } else {
        #pragma unroll
        for (int j = 0; j < 9; ++j) {
            const long long g = base + L + (long long)j * 64;
            if (g < n_f4) __builtin_nontemporal_store(r[j], out4 + g);
        }
    }
}

extern "C" void kernel_launch(void* const* d_in, const int* in_sizes, int n_in,
                              void* d_out, int out_size, void* d_ws, size_t ws_size,
                              hipStream_t stream) {
    const float* x = (const float*)d_in[0];   // [N,9] fp32
    const float* w = (const float*)d_in[1];   // [8,1,1,3,3] fp32
    const float* b = (const float*)d_in[2];   // [8] fp32
    float* out = (float*)d_out;
    float* aff = (float*)d_ws;                // 90 floats

    const long long n_elems = (long long)in_sizes[0];   // 36,000,000
    const long long n_f4    = n_elems / 4;              // 9,000,000
    const long long tiles   = (n_f4 + 575) / 576;       // 15,625 (exact)

    compose_affine<<<1, 128, 0, stream>>>(w, b, aff);
    apply_affine<<<dim3((unsigned)tiles), dim3(64), 0, stream>>>(
        (const v4f*)x, aff, (v4f*)out, n_f4);
}